// Round 10
// baseline (258.714 us; speedup 1.0000x reference)
//
#include <hip/hip_runtime.h>

// Causal depthwise conv1d: y[b,s,h] = sum_j x[b,s-3+j,h] * w[h,j], * mask[b,s]
// B=4, S=4096, H=2048, K=4, fp32.
//
// R12 post-mortem: DMA double-buffer with counted vmcnt (allocator fully
// bypassed, LDS=64KB, VGPR=52, WRITE normal) = SAME 81us / 2.55 TB/s as R3/R8/
// R11. Four verified-different issue structures, one number. Shared property:
// all keep reads+writes CONCURRENTLY in flight. Pure-write fill = 6.7 TB/s on
// this chip. R13 (last falsifier before declaring roofline): strict temporal
// alternation. 256 blocks (1/CU, 128KiB LDS), 64 rows in 4 epochs:
//   [vmcnt(0): stores drained] -> [DMA 128KiB tile, vmcnt(0)] -> [issue 16
//   nt-stores, no wait] -> compute
// Read window: 16KB/wave fire-and-forget burst (128KB/CU in flight, 8x R12).
// Predict (win): dur 50-62us, BW>=3.5 TB/s, VGPR 110-140, LDS 131072.
// Pre-commit: ~80us with gates confirmed => <<ROOFLINE>> next round.

constexpr int B_    = 4;
constexpr int S_    = 4096;
constexpr int H_    = 2048;
constexpr int H4    = H_ / 4;              // 512 float4 per row
constexpr int TPB   = 512;                 // thread t == column h4
constexpr int EROWS = 16;                  // rows per epoch (128 KiB tile)
constexpr int NEP   = 4;                   // epochs per block
constexpr int SPANR = EROWS * NEP;         // 64 rows per block
constexpr int NBLK  = (B_ * S_) / SPANR;   // 256 blocks = exactly 1 per CU
constexpr int LDS4  = EROWS * H4;          // 8192 float4 = 128 KiB

typedef float f32x4 __attribute__((ext_vector_type(4)));

// Stage a 16-row (128 KiB) tile via direct-to-LDS DMA. Per wave: 16 ops x 1KB.
// LDS dest is wave-uniform base + lane*16 (m104) == linear layout of gsrc.
__device__ __forceinline__ void stage16(const float4* gsrc, float4* lbuf,
                                        int wv, int ln) {
    #pragma unroll
    for (int j = 0; j < 16; ++j) {
        const int fo = (wv * 16 + j) * 64;             // float4 offset of 1KB chunk
        __builtin_amdgcn_global_load_lds(
            (const __attribute__((address_space(1))) void*)(gsrc + fo + ln),
            (__attribute__((address_space(3))) void*)(lbuf + fo),
            16, 0, 0);
    }
}

__global__ __launch_bounds__(TPB, 2) void budgie_dwconv1d_kernel(
    const float* __restrict__ x,     // [B,S,H]
    const float* __restrict__ w,     // [H,K]
    const float* __restrict__ mask,  // [B,S]
    float* __restrict__ y)           // [B,S,H]
{
    __shared__ float4 lbuf[LDS4];                      // 128 KiB -> 1 block/CU

    const int t  = threadIdx.x;                        // column h4, 0..511
    const int wv = t >> 6;                             // wave id 0..7
    const int ln = t & 63;                             // lane id
    const int r0 = blockIdx.x * SPANR;                 // first row of span

    const float4* x4 = (const float4*)x;
    const float4* w4 = (const float4*)w;
    f32x4* y4 = (f32x4*)y;

    // Per-channel taps (column t loop-invariant).
    const float4 w0 = w4[t * 4 + 0];
    const float4 w1 = w4[t * 4 + 1];
    const float4 w2 = w4[t * 4 + 2];
    const float4 w3 = w4[t * 4 + 3];

    const float4 zero4 = make_float4(0.f, 0.f, 0.f, 0.f);

    // Sliding window regs: rows r-3, r-2, r-1 of column t (carried across epochs).
    float4 wm3, wm2, wm1;
    if ((r0 & (S_ - 1)) != 0) {                        // uniform; ==0 iff batch start
        wm1 = x4[(long)(r0 - 1) * H4 + t];
        wm2 = x4[(long)(r0 - 2) * H4 + t];
        wm3 = x4[(long)(r0 - 3) * H4 + t];
    } else {
        wm1 = wm2 = wm3 = zero4;                       // causal zero-pad
    }

    // Prologue: pure-read epoch 0 (halo loads drain with it).
    stage16(x4 + (long)r0 * H4, lbuf, wv, ln);
    asm volatile("s_waitcnt vmcnt(0)" ::: "memory");
    __builtin_amdgcn_sched_barrier(0);

    #pragma unroll
    for (int e = 0; e < NEP; ++e) {
        const int R  = r0 + e * EROWS;
        const int Ru = __builtin_amdgcn_readfirstlane(R);   // mask via s_load

        __builtin_amdgcn_s_barrier();                  // LDS[e] valid for all waves
        // ---- compute phase: 16 rows -> o[] (held in regs until write burst) ----
        f32x4 o[EROWS];                                // 64 VGPRs, static idx only
        #pragma unroll
        for (int r = 0; r < EROWS; ++r) {
            const float4 cur = lbuf[r * H4 + t];       // ds_read_b128, conflict-free
            const float  m   = mask[Ru + r];
            o[r].x = fmaf(wm3.x, w0.x, fmaf(wm2.x, w0.y, fmaf(wm1.x, w0.z, cur.x * w0.w)));
            o[r].y = fmaf(wm3.y, w1.x, fmaf(wm2.y, w1.y, fmaf(wm1.y, w1.z, cur.y * w1.w)));
            o[r].z = fmaf(wm3.z, w2.x, fmaf(wm2.z, w2.y, fmaf(wm1.z, w2.z, cur.z * w2.w)));
            o[r].w = fmaf(wm3.w, w3.x, fmaf(wm2.w, w3.y, fmaf(wm1.w, w3.z, cur.w * w3.w)));
            o[r].x *= m; o[r].y *= m; o[r].z *= m; o[r].w *= m;
            wm3 = wm2; wm2 = wm1; wm1 = cur;           // window rotate (regs)
        }
        __builtin_amdgcn_s_barrier();                  // all waves done reading LDS[e]

        // ---- pure-write tail: previous epoch's stores drain alone ----
        asm volatile("s_waitcnt vmcnt(0)" ::: "memory");
        __builtin_amdgcn_sched_barrier(0);

        // ---- pure-read epoch: DMA tile e+1, wait it out (reads service alone) ----
        if (e + 1 < NEP)
            stage16(x4 + (long)(R + EROWS) * H4, lbuf, wv, ln);
        asm volatile("s_waitcnt vmcnt(0)" ::: "memory");
        __builtin_amdgcn_sched_barrier(0);

        // ---- write burst: fire and forget (drains during next compute + drain) ----
        #pragma unroll
        for (int r = 0; r < EROWS; ++r)
            __builtin_nontemporal_store(o[r], y4 + (long)(R + r) * H4 + t);
    }
}

extern "C" void kernel_launch(void* const* d_in, const int* in_sizes, int n_in,
                              void* d_out, int out_size, void* d_ws, size_t ws_size,
                              hipStream_t stream) {
    const float* x    = (const float*)d_in[0];   // hidden_states [B,S,H]
    const float* w    = (const float*)d_in[1];   // weight [H,K]
    const float* mask = (const float*)d_in[2];   // attention_mask_2d [B,S]
    float* y = (float*)d_out;

    budgie_dwconv1d_kernel<<<dim3(NBLK), TPB, 0, stream>>>(x, w, mask, y);
}

// Round 11
// 233.848 us; speedup vs baseline: 1.1063x; 1.1063x over previous
//
#include <hip/hip_runtime.h>

// Causal depthwise conv1d: y[b,s,h] = sum_j x[b,s-3+j,h] * w[h,j], * mask[b,s]
// B=4, S=4096, H=2048, K=4, fp32.
//
// R13 structure (temporal read/write separation) — RESUBMIT UNCHANGED for clean
// measurement. R13's bench ran on a degraded container (fills 5.1 TB/s vs 6.6
// every other round). Deconfounding via bench≈kernel+2*fill (verified on
// R9/R10/R12 within ~3us): kernel ≈ 258.7-208.8 ≈ 50us on the SLOW machine,
// vs 106us for R12's structure there => the strict alternation of pure-read
// epochs (128KiB/CU DMA burst, vmcnt(0)) and pure-write epochs (nt-store burst,
// drained alone) broke the 2.6 TB/s concurrent-R/W wall. Expect ~38-48us here.
// Serialized-stream bound: 268MB / 6.3TB/s = 42.5us — if confirmed, that IS the
// roofline (a copy of the same bytes takes the same time).
//
//   per epoch: [vmcnt(0): stores drained] -> [DMA 128KiB tile, vmcnt(0)] ->
//              [issue 16 nt-stores, no wait] -> compute next
// 256 blocks = 1/CU (128KiB LDS), 64 rows in 4 epochs of 16.
// Gates: LDS 131072, VGPR 110-140, occupancy ~25% (by design), WRITE ~131MB.

constexpr int B_    = 4;
constexpr int S_    = 4096;
constexpr int H_    = 2048;
constexpr int H4    = H_ / 4;              // 512 float4 per row
constexpr int TPB   = 512;                 // thread t == column h4
constexpr int EROWS = 16;                  // rows per epoch (128 KiB tile)
constexpr int NEP   = 4;                   // epochs per block
constexpr int SPANR = EROWS * NEP;         // 64 rows per block
constexpr int NBLK  = (B_ * S_) / SPANR;   // 256 blocks = exactly 1 per CU
constexpr int LDS4  = EROWS * H4;          // 8192 float4 = 128 KiB

typedef float f32x4 __attribute__((ext_vector_type(4)));

// Stage a 16-row (128 KiB) tile via direct-to-LDS DMA. Per wave: 16 ops x 1KB.
// LDS dest is wave-uniform base + lane*16 (m104) == linear layout of gsrc.
__device__ __forceinline__ void stage16(const float4* gsrc, float4* lbuf,
                                        int wv, int ln) {
    #pragma unroll
    for (int j = 0; j < 16; ++j) {
        const int fo = (wv * 16 + j) * 64;             // float4 offset of 1KB chunk
        __builtin_amdgcn_global_load_lds(
            (const __attribute__((address_space(1))) void*)(gsrc + fo + ln),
            (__attribute__((address_space(3))) void*)(lbuf + fo),
            16, 0, 0);
    }
}

__global__ __launch_bounds__(TPB, 2) void budgie_dwconv1d_kernel(
    const float* __restrict__ x,     // [B,S,H]
    const float* __restrict__ w,     // [H,K]
    const float* __restrict__ mask,  // [B,S]
    float* __restrict__ y)           // [B,S,H]
{
    __shared__ float4 lbuf[LDS4];                      // 128 KiB -> 1 block/CU

    const int t  = threadIdx.x;                        // column h4, 0..511
    const int wv = t >> 6;                             // wave id 0..7
    const int ln = t & 63;                             // lane id
    const int r0 = blockIdx.x * SPANR;                 // first row of span

    const float4* x4 = (const float4*)x;
    const float4* w4 = (const float4*)w;
    f32x4* y4 = (f32x4*)y;

    // Per-channel taps (column t loop-invariant).
    const float4 w0 = w4[t * 4 + 0];
    const float4 w1 = w4[t * 4 + 1];
    const float4 w2 = w4[t * 4 + 2];
    const float4 w3 = w4[t * 4 + 3];

    const float4 zero4 = make_float4(0.f, 0.f, 0.f, 0.f);

    // Sliding window regs: rows r-3, r-2, r-1 of column t (carried across epochs).
    float4 wm3, wm2, wm1;
    if ((r0 & (S_ - 1)) != 0) {                        // uniform; ==0 iff batch start
        wm1 = x4[(long)(r0 - 1) * H4 + t];
        wm2 = x4[(long)(r0 - 2) * H4 + t];
        wm3 = x4[(long)(r0 - 3) * H4 + t];
    } else {
        wm1 = wm2 = wm3 = zero4;                       // causal zero-pad
    }

    // Prologue: pure-read epoch 0 (halo loads drain with it).
    stage16(x4 + (long)r0 * H4, lbuf, wv, ln);
    asm volatile("s_waitcnt vmcnt(0)" ::: "memory");
    __builtin_amdgcn_sched_barrier(0);

    #pragma unroll
    for (int e = 0; e < NEP; ++e) {
        const int R  = r0 + e * EROWS;
        const int Ru = __builtin_amdgcn_readfirstlane(R);   // mask via s_load

        __builtin_amdgcn_s_barrier();                  // LDS[e] valid for all waves
        // ---- compute phase: 16 rows -> o[] (held in regs until write burst) ----
        f32x4 o[EROWS];                                // 64 VGPRs, static idx only
        #pragma unroll
        for (int r = 0; r < EROWS; ++r) {
            const float4 cur = lbuf[r * H4 + t];       // ds_read_b128, conflict-free
            const float  m   = mask[Ru + r];
            o[r].x = fmaf(wm3.x, w0.x, fmaf(wm2.x, w0.y, fmaf(wm1.x, w0.z, cur.x * w0.w)));
            o[r].y = fmaf(wm3.y, w1.x, fmaf(wm2.y, w1.y, fmaf(wm1.y, w1.z, cur.y * w1.w)));
            o[r].z = fmaf(wm3.z, w2.x, fmaf(wm2.z, w2.y, fmaf(wm1.z, w2.z, cur.z * w2.w)));
            o[r].w = fmaf(wm3.w, w3.x, fmaf(wm2.w, w3.y, fmaf(wm1.w, w3.z, cur.w * w3.w)));
            o[r].x *= m; o[r].y *= m; o[r].z *= m; o[r].w *= m;
            wm3 = wm2; wm2 = wm1; wm1 = cur;           // window rotate (regs)
        }
        __builtin_amdgcn_s_barrier();                  // all waves done reading LDS[e]

        // ---- pure-write tail: previous epoch's stores drain alone ----
        asm volatile("s_waitcnt vmcnt(0)" ::: "memory");
        __builtin_amdgcn_sched_barrier(0);

        // ---- pure-read epoch: DMA tile e+1, wait it out (reads service alone) ----
        if (e + 1 < NEP)
            stage16(x4 + (long)(R + EROWS) * H4, lbuf, wv, ln);
        asm volatile("s_waitcnt vmcnt(0)" ::: "memory");
        __builtin_amdgcn_sched_barrier(0);

        // ---- write burst: fire and forget (drains during next compute + drain) ----
        #pragma unroll
        for (int r = 0; r < EROWS; ++r)
            __builtin_nontemporal_store(o[r], y4 + (long)(R + r) * H4 + t);
    }
}

extern "C" void kernel_launch(void* const* d_in, const int* in_sizes, int n_in,
                              void* d_out, int out_size, void* d_ws, size_t ws_size,
                              hipStream_t stream) {
    const float* x    = (const float*)d_in[0];   // hidden_states [B,S,H]
    const float* w    = (const float*)d_in[1];   // weight [H,K]
    const float* mask = (const float*)d_in[2];   // attention_mask_2d [B,S]
    float* y = (float*)d_out;

    budgie_dwconv1d_kernel<<<dim3(NBLK), TPB, 0, stream>>>(x, w, mask, y);
}